// Round 4
// baseline (61.581 us; speedup 1.0000x reference)
//
#include <hip/hip_runtime.h>

#define VOCAB 32000
#define EMB   1024
#define TPB   512
#define COLS  32                  // vocab cols per tile = one aligned 128B line per W row
#define TILES (VOCAB / COLS)      // 1000
#define CH    128                 // emb rows per LDS chunk
#define PITCH 130                 // floats; write banks 2-way (free), rows 8B-aligned
#define CAP_T 256                 // per-tile bucket capacity (expected ~33 matches)

typedef float f32x4 __attribute__((ext_vector_type(4)));

// ---------------------------------------------------------------------------
// Pass 0: zero the per-tile counters (d_ws is poisoned, not zeroed).
// ---------------------------------------------------------------------------
__global__ __launch_bounds__(TPB) void tok_emb_zero(int* __restrict__ cnt) {
    const int i = blockIdx.x * TPB + threadIdx.x;
    if (i < TILES) cnt[i] = 0;
}

// ---------------------------------------------------------------------------
// Pass 1: bucket tokens by vocab tile. List order is nondeterministic
// (atomics) but the consumer is order-independent.
// ---------------------------------------------------------------------------
__global__ __launch_bounds__(TPB) void tok_emb_bucket(
    const int* __restrict__ tokens, int* __restrict__ cnt,
    int* __restrict__ bucket, int n_tokens) {
    const int i4 = (blockIdx.x * TPB + threadIdx.x) * 4;
    if (i4 + 3 < n_tokens) {
        const int4 tk = *reinterpret_cast<const int4*>(&tokens[i4]);
        const int tv[4] = {tk.x, tk.y, tk.z, tk.w};
#pragma unroll
        for (int j = 0; j < 4; ++j) {
            const int tok = tv[j];
            const unsigned tile = (unsigned)tok >> 5;
            if (tile < TILES) {
                const int p = atomicAdd(&cnt[tile], 1);
                if (p < CAP_T) bucket[tile * CAP_T + p] = ((i4 + j) << 5) | (tok & 31);
            }
        }
    } else {
        for (int i = i4; i < n_tokens; ++i) {
            const int tok = tokens[i];
            const unsigned tile = (unsigned)tok >> 5;
            if (tile < TILES) {
                const int p = atomicAdd(&cnt[tile], 1);
                if (p < CAP_T) bucket[tile * CAP_T + p] = (i << 5) | (tok & 31);
            }
        }
    }
}

// ---------------------------------------------------------------------------
// Pass 2: per tile, stage W[:, v0:v0+32] transposed in LDS chunk-by-chunk,
// stream each matched token's row segment out (nontemporal, coalesced).
// ---------------------------------------------------------------------------
__global__ __launch_bounds__(TPB) void tok_emb_main(
    const float* __restrict__ W, const int* __restrict__ tokens,
    const int* __restrict__ cnt, const int* __restrict__ bucket,
    f32x4* __restrict__ out4, int n_tokens) {
    __shared__ float lds[COLS * PITCH];   // 16.6 KB
    __shared__ int   list[CAP_T];         // 1 KB
    __shared__ int   scnt;

    const int tile = blockIdx.x;
    const int v0   = tile * COLS;
    const int tid  = threadIdx.x;

    auto process = [&](int m) {
        if (m == 0) return;
        for (int c0 = 0; c0 < EMB; c0 += CH) {
            __syncthreads();             // prior chunk's readers done
#pragma unroll
            for (int it = 0; it < (CH * COLS / 4) / TPB; ++it) {  // 2 iters
                const int idx = tid + it * TPB;
                const int r   = idx >> 3;        // emb row in chunk, 0..127
                const int cc  = (idx & 7) << 2;  // col group of 4
                const float4 v = *reinterpret_cast<const float4*>(
                    &W[(size_t)(c0 + r) * VOCAB + (size_t)(v0 + cc)]);
                lds[(cc + 0) * PITCH + r] = v.x;
                lds[(cc + 1) * PITCH + r] = v.y;
                lds[(cc + 2) * PITCH + r] = v.z;
                lds[(cc + 3) * PITCH + r] = v.w;
            }
            __syncthreads();

            const int total = m << 5;    // m tokens * 32 float4 per chunk
            for (int j = tid; j < total; j += TPB) {
                const int mi = j >> 5, lane = j & 31;
                const int ent = list[mi];
                const int t   = ent >> 5, col = ent & 31;
                const float* rp = &lds[col * PITCH + (lane << 2)];
                const float2 a = *reinterpret_cast<const float2*>(rp);
                const float2 b = *reinterpret_cast<const float2*>(rp + 2);
                f32x4 o;
                o.x = a.x; o.y = a.y; o.z = b.x; o.w = b.y;
                __builtin_nontemporal_store(
                    o, &out4[(size_t)t * (EMB / 4) + (c0 >> 2) + lane]);
            }
        }
    };

    const int m_total = (bucket != nullptr) ? cnt[tile] : CAP_T + 1;
    if (m_total <= CAP_T) {
        for (int j = tid; j < m_total; j += TPB) list[j] = bucket[tile * CAP_T + j];
        __syncthreads();
        process(m_total);
    } else {
        // Structural backstop (ws too small or >CAP_T matches in one tile):
        // segment of CAP_T tokens can never overflow the list.
        for (int lo = 0; lo < n_tokens; lo += CAP_T) {
            const int hi = (lo + CAP_T < n_tokens) ? lo + CAP_T : n_tokens;
            __syncthreads();
            if (tid == 0) scnt = 0;
            __syncthreads();
            for (int i = lo + tid; i < hi; i += TPB) {
                const unsigned d = (unsigned)(tokens[i] - v0);
                if (d < COLS) {
                    const int p = atomicAdd(&scnt, 1);
                    list[p] = (i << 5) | (int)d;
                }
            }
            __syncthreads();
            process(scnt);
        }
    }
}

extern "C" void kernel_launch(void* const* d_in, const int* in_sizes, int n_in,
                              void* d_out, int out_size, void* d_ws, size_t ws_size,
                              hipStream_t stream) {
    const int*   tokens   = (const int*)d_in[0];   // [8*4096] int32
    const float* W        = (const float*)d_in[1]; // [1024][32000] f32
    f32x4*       out4     = (f32x4*)d_out;         // [32768][1024] f32
    const int    n_tokens = in_sizes[0];

    const size_t need = (size_t)TILES * sizeof(int)
                      + (size_t)TILES * CAP_T * sizeof(int);
    if (ws_size >= need) {
        int* cnt    = (int*)d_ws;
        int* bucket = cnt + TILES;
        tok_emb_zero<<<(TILES + TPB - 1) / TPB, TPB, 0, stream>>>(cnt);
        const int quads = (n_tokens + 3) / 4;
        tok_emb_bucket<<<(quads + TPB - 1) / TPB, TPB, 0, stream>>>(
            tokens, cnt, bucket, n_tokens);
        tok_emb_main<<<TILES, TPB, 0, stream>>>(W, tokens, cnt, bucket, out4, n_tokens);
    } else {
        tok_emb_main<<<TILES, TPB, 0, stream>>>(W, tokens, nullptr, nullptr, out4, n_tokens);
    }
}